// Round 1
// baseline (1019.394 us; speedup 1.0000x reference)
//
#include <hip/hip_runtime.h>
#include <hip/hip_bf16.h>
#include <math.h>
#include <stdint.h>

#define B_ 4
#define T_ 1024
#define S_ 1024
#define D_ 1024
#define H_ 16
#define DH_ 64

static constexpr float EPSV = 1e-5f;

// ---------------------------------------------------------------------------
// Tiled NT GEMM: Y = X @ W^T (X: [4096, 1024] rows, W: [1024,1024] row-major).
// HEADSPLIT=1: write Y into head-split layout [B,H,T,DH] (with scale).
// HEADSPLIT=0: write Y flat [4096,1024] (with scale).
// Block: 256 threads, 64x64 tile, 4x4 per thread, K-step 16.
// ---------------------------------------------------------------------------
template <int HEADSPLIT>
__global__ __launch_bounds__(256) void k_proj(const float* __restrict__ X,
                                              const float* __restrict__ W,
                                              float* __restrict__ Y,
                                              float scale) {
  __shared__ float Xs[16][68];
  __shared__ float Ws[16][68];
  const int tid = threadIdx.x;
  const int i0 = blockIdx.x << 6;
  const int j0 = blockIdx.y << 6;
  const int lr = tid >> 2;          // 0..63 row within tile
  const int lk = (tid & 3) << 2;    // 0,4,8,12 k-offset
  const int tx = tid & 15;
  const int ty = tid >> 4;
  float acc[4][4] = {{0.f}};

  for (int k0 = 0; k0 < D_; k0 += 16) {
    float4 xv = *(const float4*)(X + (size_t)(i0 + lr) * D_ + k0 + lk);
    float4 wv = *(const float4*)(W + (size_t)(j0 + lr) * D_ + k0 + lk);
    __syncthreads();
    Xs[lk + 0][lr] = xv.x; Xs[lk + 1][lr] = xv.y;
    Xs[lk + 2][lr] = xv.z; Xs[lk + 3][lr] = xv.w;
    Ws[lk + 0][lr] = wv.x; Ws[lk + 1][lr] = wv.y;
    Ws[lk + 2][lr] = wv.z; Ws[lk + 3][lr] = wv.w;
    __syncthreads();
#pragma unroll
    for (int kk = 0; kk < 16; ++kk) {
      float4 av = *(const float4*)&Xs[kk][ty << 2];
      float4 bv = *(const float4*)&Ws[kk][tx << 2];
      const float aa[4] = {av.x, av.y, av.z, av.w};
      const float bb[4] = {bv.x, bv.y, bv.z, bv.w};
#pragma unroll
      for (int r = 0; r < 4; ++r)
#pragma unroll
        for (int c = 0; c < 4; ++c)
          acc[r][c] = fmaf(aa[r], bb[c], acc[r][c]);
    }
  }

#pragma unroll
  for (int r = 0; r < 4; ++r) {
    const int i = i0 + (ty << 2) + r;
    float4 o;
    o.x = acc[r][0] * scale; o.y = acc[r][1] * scale;
    o.z = acc[r][2] * scale; o.w = acc[r][3] * scale;
    if (HEADSPLIT) {
      // j0 is 64-aligned -> head h = blockIdx.y, dh = 4*tx + c
      const int b = i >> 10, t = i & 1023;
      float* dst = Y + (((size_t)(b * H_ + blockIdx.y) * T_) + t) * DH_ + (tx << 2);
      *(float4*)dst = o;
    } else {
      *(float4*)(Y + (size_t)i * D_ + j0 + (tx << 2)) = o;
    }
  }
}

// ---------------------------------------------------------------------------
// Column stats: for each (b,s), partial (max, sumexp) over a 64-t-tile of one
// head. grid = (S/64, T/64, B*H). 256 partials per (b,s) column.
// ---------------------------------------------------------------------------
__global__ __launch_bounds__(256) void k_colstats(const float* __restrict__ Qh,
                                                  const float* __restrict__ Kh,
                                                  const float* __restrict__ bias,
                                                  const int* __restrict__ mask,
                                                  float* __restrict__ pm,
                                                  float* __restrict__ pc) {
  const int bh = blockIdx.z;
  const int b = bh >> 4, h = bh & 15;
  const int s0 = blockIdx.x << 6;
  const int t0 = blockIdx.y << 6;
  const int tid = threadIdx.x;
  __shared__ float Qt[64][64];   // broadcast-read only
  __shared__ float Ks[64][68];   // per-lane row -> padded
  __shared__ float rm[4][64], rc[4][64];
  {
    const float* qsrc = Qh + ((size_t)(b * H_ + h) * T_ + t0) * DH_;
    const float* ksrc = Kh + ((size_t)(b * H_ + h) * S_ + s0) * DH_;
#pragma unroll
    for (int u = 0; u < 4; ++u) {
      const int lin = (u << 10) + (tid << 2);
      const int r = lin >> 6, cc = lin & 63;
      *(float4*)&Qt[r][cc] = *(const float4*)(qsrc + lin);
      *(float4*)&Ks[r][cc] = *(const float4*)(ksrc + lin);
    }
  }
  __syncthreads();
  const int s = tid & 63;
  const int tg = tid >> 6;
  float kr[64];
#pragma unroll
  for (int d = 0; d < 64; d += 4) {
    float4 kv = *(const float4*)&Ks[s][d];
    kr[d] = kv.x; kr[d + 1] = kv.y; kr[d + 2] = kv.z; kr[d + 3] = kv.w;
  }
  float m = -INFINITY, c = 0.f;
#pragma unroll 1
  for (int j = 0; j < 16; ++j) {
    const int t = (tg << 4) + j;
    const int mk = mask[(size_t)(t0 + t) * S_ + s0 + s];
    float x = 0.f;
#pragma unroll
    for (int d = 0; d < 64; d += 4) {
      float4 qv = *(const float4*)&Qt[t][d];
      x = fmaf(qv.x, kr[d], x);
      x = fmaf(qv.y, kr[d + 1], x);
      x = fmaf(qv.z, kr[d + 2], x);
      x = fmaf(qv.w, kr[d + 3], x);
    }
    x += bias[((size_t)h * T_ + t0 + t) * S_ + s0 + s];
    if (!mk) {
      if (x > m) { c = c * __expf(m - x) + 1.f; m = x; }
      else       { c += __expf(x - m); }
    }
  }
  rm[tg][s] = m; rc[tg][s] = c;
  __syncthreads();
  if (tg == 0) {
    float M = m, C = c;
#pragma unroll
    for (int g = 1; g < 4; ++g) {
      const float mg = rm[g][s], cg = rc[g][s];
      if (mg > M) { C = C * __expf(M - mg) + cg; M = mg; }
      else if (cg > 0.f) { C += cg * __expf(mg - M); }
    }
    const size_t base = ((size_t)b * S_ + s0 + s) * 256 + (h << 4) + blockIdx.y;
    pm[base] = M; pc[base] = C;
  }
}

// ---------------------------------------------------------------------------
// Combine 256 partials per (b,s) -> M, C.
// ---------------------------------------------------------------------------
__global__ __launch_bounds__(256) void k_combine(const float* __restrict__ pm,
                                                 const float* __restrict__ pc,
                                                 float* __restrict__ Mout,
                                                 float* __restrict__ Cout) {
  const int bs = blockIdx.x;
  const int tid = threadIdx.x;
  const size_t base = (size_t)bs * 256;
  const float m = pm[base + tid];
  const float c = pc[base + tid];
  __shared__ float sm[256], sc[256];
  sm[tid] = m;
  __syncthreads();
  for (int off = 128; off > 0; off >>= 1) {
    if (tid < off) sm[tid] = fmaxf(sm[tid], sm[tid + off]);
    __syncthreads();
  }
  const float M = sm[0];
  __syncthreads();
  sc[tid] = (c > 0.f) ? c * __expf(m - M) : 0.f;
  __syncthreads();
  for (int off = 128; off > 0; off >>= 1) {
    if (tid < off) sc[tid] += sc[tid + off];
    __syncthreads();
  }
  if (tid == 0) { Mout[bs] = M; Cout[bs] = sc[0]; }
}

// ---------------------------------------------------------------------------
// Attention pass: per (b,h,64-t-tile): recompute scores, p = exp(x-M)/C
// (0 if masked), accumulate R and P@V, write O[b,t,h*64+d] = acc/(R+EPS).
// ---------------------------------------------------------------------------
__global__ __launch_bounds__(256) void k_attn(const float* __restrict__ Qh,
                                              const float* __restrict__ Kh,
                                              const float* __restrict__ Vh,
                                              const float* __restrict__ bias,
                                              const int* __restrict__ mask,
                                              const float* __restrict__ Mv,
                                              const float* __restrict__ Cv,
                                              float* __restrict__ O) {
  const int b = blockIdx.z;
  const int h = blockIdx.y;
  const int t0 = blockIdx.x << 6;
  const int tid = threadIdx.x;

  __shared__ float Qt[64][68];
  __shared__ float Ks[64][68];
  __shared__ float Vs[64][68];
  __shared__ float Pt[64][68];   // [s][t]
  __shared__ float Ms[64], Ci[64];
  __shared__ float Rp[4][64];

  const int tl = tid & 63;      // phase1: this thread's t
  const int sg = tid >> 6;      // phase1: s-group (16 s each)
  const int dg = tid & 15;      // phase2: d-quad
  const int tq = tid >> 4;      // phase2: t-quad (0..15)

  {
    const float* src = Qh + ((size_t)(b * H_ + h) * T_ + t0) * DH_;
#pragma unroll
    for (int u = 0; u < 4; ++u) {
      const int lin = (u << 10) + (tid << 2);
      const int r = lin >> 6, cc = lin & 63;
      *(float4*)&Qt[r][cc] = *(const float4*)(src + lin);
    }
  }
  __syncthreads();
  float qr[64];
#pragma unroll
  for (int d = 0; d < 64; d += 4) {
    float4 qv = *(const float4*)&Qt[tl][d];
    qr[d] = qv.x; qr[d + 1] = qv.y; qr[d + 2] = qv.z; qr[d + 3] = qv.w;
  }

  float acc[4][4] = {{0.f}};
  float rloc = 0.f;
  const size_t kvbase = ((size_t)(b * H_ + h) * S_) * DH_;

#pragma unroll 1
  for (int st = 0; st < 16; ++st) {
    const int ss0 = st << 6;
    __syncthreads();   // protect Pt/Vs from previous phase2 readers
#pragma unroll
    for (int u = 0; u < 4; ++u) {
      const int lin = (u << 10) + (tid << 2);
      const int r = lin >> 6, cc = lin & 63;
      *(float4*)&Ks[r][cc] = *(const float4*)(Kh + kvbase + (size_t)ss0 * DH_ + lin);
      *(float4*)&Vs[r][cc] = *(const float4*)(Vh + kvbase + (size_t)ss0 * DH_ + lin);
    }
    if (tid < 64) {
      Ms[tid] = Mv[(size_t)b * S_ + ss0 + tid];
      Ci[tid] = 1.f / Cv[(size_t)b * S_ + ss0 + tid];
    }
    __syncthreads();
    // phase 1: scores for t = tl, s = sg*16 + 0..15
    {
      const float* brow = bias + ((size_t)h * T_ + (t0 + tl)) * S_ + ss0 + (sg << 4);
      const int* mrow = mask + (size_t)(t0 + tl) * S_ + ss0 + (sg << 4);
#pragma unroll 1
      for (int jj = 0; jj < 4; ++jj) {
        const float4 bv = *(const float4*)(brow + (jj << 2));
        const int4 mv4 = *(const int4*)(mrow + (jj << 2));
        const float bb[4] = {bv.x, bv.y, bv.z, bv.w};
        const int mm[4] = {mv4.x, mv4.y, mv4.z, mv4.w};
#pragma unroll
        for (int j2 = 0; j2 < 4; ++j2) {
          const int sv = (sg << 4) + (jj << 2) + j2;
          float x = 0.f;
#pragma unroll
          for (int d = 0; d < 64; d += 4) {
            const float4 kv = *(const float4*)&Ks[sv][d];
            x = fmaf(qr[d], kv.x, x);
            x = fmaf(qr[d + 1], kv.y, x);
            x = fmaf(qr[d + 2], kv.z, x);
            x = fmaf(qr[d + 3], kv.w, x);
          }
          x += bb[j2];
          const float p = mm[j2] ? 0.f : __expf(x - Ms[sv]) * Ci[sv];
          Pt[sv][tl] = p;
          rloc += p;
        }
      }
    }
    __syncthreads();
    // phase 2: acc[r][c] += P[s][4tq+r] * V[s][4dg+c]
#pragma unroll 4
    for (int sv = 0; sv < 64; ++sv) {
      const float4 pv = *(const float4*)&Pt[sv][tq << 2];
      const float4 vv = *(const float4*)&Vs[sv][dg << 2];
      const float pp[4] = {pv.x, pv.y, pv.z, pv.w};
      const float vb[4] = {vv.x, vv.y, vv.z, vv.w};
#pragma unroll
      for (int r = 0; r < 4; ++r)
#pragma unroll
        for (int c = 0; c < 4; ++c)
          acc[r][c] = fmaf(pp[r], vb[c], acc[r][c]);
    }
  }

  Rp[sg][tl] = rloc;
  __syncthreads();
#pragma unroll
  for (int r = 0; r < 4; ++r) {
    const int t = (tq << 2) + r;
    const float R = Rp[0][t] + Rp[1][t] + Rp[2][t] + Rp[3][t];
    const float rinv = 1.f / (R + EPSV);
    float4 o;
    o.x = acc[r][0] * rinv; o.y = acc[r][1] * rinv;
    o.z = acc[r][2] * rinv; o.w = acc[r][3] * rinv;
    *(float4*)(O + ((size_t)(b * T_) + t0 + t) * D_ + h * DH_ + (dg << 2)) = o;
  }
}

// ---------------------------------------------------------------------------
extern "C" void kernel_launch(void* const* d_in, const int* in_sizes, int n_in,
                              void* d_out, int out_size, void* d_ws, size_t ws_size,
                              hipStream_t stream) {
  const float* q    = (const float*)d_in[0];
  const float* k    = (const float*)d_in[1];
  const float* v    = (const float*)d_in[2];
  const int*   mask = (const int*)d_in[3];
  const float* bias = (const float*)d_in[4];
  const float* Wq   = (const float*)d_in[5];
  const float* Wk   = (const float*)d_in[6];
  const float* Wv   = (const float*)d_in[7];
  const float* Wo   = (const float*)d_in[8];
  float* out = (float*)d_out;

  float* ws = (float*)d_ws;
  const size_t NE = (size_t)B_ * T_ * D_;  // 4,194,304
  float* Qh = ws;
  float* Kh = Qh + NE;
  float* Vh = Kh + NE;
  float* O  = Vh + NE;
  float* pm = O + NE;                       // B*S*256 = 1,048,576
  float* pc = pm + (size_t)B_ * S_ * 256;
  float* Mv = pc + (size_t)B_ * S_ * 256;   // B*S
  float* Cv = Mv + (size_t)B_ * S_;

  const dim3 gp(64, 16);
  k_proj<1><<<gp, 256, 0, stream>>>(q, Wq, Qh, 0.125f);
  k_proj<1><<<gp, 256, 0, stream>>>(k, Wk, Kh, 1.0f);
  k_proj<1><<<gp, 256, 0, stream>>>(v, Wv, Vh, 1.0f);

  k_colstats<<<dim3(16, 16, 64), 256, 0, stream>>>(Qh, Kh, bias, mask, pm, pc);
  k_combine<<<dim3(B_ * S_), 256, 0, stream>>>(pm, pc, Mv, Cv);
  k_attn<<<dim3(16, 16, 4), 256, 0, stream>>>(Qh, Kh, Vh, bias, mask, Mv, Cv, O);

  k_proj<0><<<gp, 256, 0, stream>>>(O, Wo, out, 1.0f);
}

// Round 2
// 642.864 us; speedup vs baseline: 1.5857x; 1.5857x over previous
//
#include <hip/hip_runtime.h>
#include <hip/hip_bf16.h>
#include <math.h>
#include <stdint.h>

#define B_ 4
#define T_ 1024
#define S_ 1024
#define D_ 1024
#define H_ 16
#define DH_ 64

static constexpr float EPSV = 1e-5f;

typedef __attribute__((ext_vector_type(8))) short short8;
typedef __attribute__((ext_vector_type(4))) float f32x4;

#define MFMA_BF16 __builtin_amdgcn_mfma_f32_16x16x32_bf16

__device__ __forceinline__ ushort f2bf(float f) {
  union { float f; unsigned u; } v; v.f = f;
  unsigned r = (v.u + 0x7FFFu + ((v.u >> 16) & 1u)) >> 16;
  return (ushort)r;
}

// combine two (max, sumexp) pairs; guards against -inf/-inf NaN
__device__ __forceinline__ void mc_comb(float& m, float& c, float mo, float co) {
  float M = fmaxf(m, mo);
  float cn = 0.f;
  if (c  > 0.f) cn += c  * __expf(m  - M);
  if (co > 0.f) cn += co * __expf(mo - M);
  m = M; c = cn;
}

// ---------------------------------------------------------------------------
// f32 -> bf16 elementwise (4 elems/thread)
// ---------------------------------------------------------------------------
__global__ __launch_bounds__(256) void k_tobf16(const float* __restrict__ x,
                                                ushort* __restrict__ y) {
  const int i = (blockIdx.x * 256 + threadIdx.x) * 4;
  float4 v = *(const float4*)(x + i);
  ushort4 o = make_ushort4(f2bf(v.x), f2bf(v.y), f2bf(v.z), f2bf(v.w));
  *(ushort4*)(y + i) = o;
}

// ---------------------------------------------------------------------------
// bf16 MFMA GEMM: Y = A[4096,1024] @ W[1024,1024]^T (both row-major bf16).
// 128x128 tile, 4 waves (2x2 of 64x64), K-step 32.
// MODE 0: write f32 flat [4096,1024] * scale (final output)
// MODE 1: write bf16 head-split [(b*16+h)*1024 + t][64] * scale
// ---------------------------------------------------------------------------
template <int MODE>
__global__ __launch_bounds__(256) void k_gemm(const ushort* __restrict__ A,
                                              const ushort* __restrict__ W,
                                              void* __restrict__ Yv,
                                              float scale) {
  __shared__ ushort At[128][40];  // stride 40 bf16 = 80 B (16B-aligned, conflict-free)
  __shared__ ushort Wt[128][40];
  const int tid = threadIdx.x;
  const int l = tid & 63, w = tid >> 6;
  const int wm = (w >> 1) * 64, wn = (w & 1) * 64;
  const int r16 = l & 15, g = l >> 4;
  const int i0 = blockIdx.x * 128, j0 = blockIdx.y * 128;
  f32x4 acc[4][4] = {};

  for (int k0 = 0; k0 < D_; k0 += 32) {
    __syncthreads();
#pragma unroll
    for (int u = 0; u < 2; ++u) {
      const int lin = u * 256 + tid;
      const int row = lin >> 2, c8 = (lin & 3) << 3;
      *(uint4*)&At[row][c8] = *(const uint4*)&A[(size_t)(i0 + row) * D_ + k0 + c8];
      *(uint4*)&Wt[row][c8] = *(const uint4*)&W[(size_t)(j0 + row) * D_ + k0 + c8];
    }
    __syncthreads();
    short8 a0[4], b0[4];
#pragma unroll
    for (int i = 0; i < 4; ++i) a0[i] = *(const short8*)&At[wm + 16 * i + r16][g * 8];
#pragma unroll
    for (int j = 0; j < 4; ++j) b0[j] = *(const short8*)&Wt[wn + 16 * j + r16][g * 8];
#pragma unroll
    for (int i = 0; i < 4; ++i)
#pragma unroll
      for (int j = 0; j < 4; ++j)
        acc[i][j] = MFMA_BF16(a0[i], b0[j], acc[i][j], 0, 0, 0);
  }

#pragma unroll
  for (int i = 0; i < 4; ++i)
#pragma unroll
    for (int j = 0; j < 4; ++j)
#pragma unroll
      for (int r = 0; r < 4; ++r) {
        const int row = i0 + wm + 16 * i + 4 * g + r;
        const int col = j0 + wn + 16 * j + r16;
        const float v = acc[i][j][r] * scale;
        if (MODE == 0) {
          ((float*)Yv)[(size_t)row * D_ + col] = v;
        } else {
          const int b = row >> 10, t = row & 1023;
          const int h = col >> 6, dh = col & 63;
          ((ushort*)Yv)[(((size_t)(b * H_ + h) * 1024) + t) * DH_ + dh] = f2bf(v);
        }
      }
}

// ---------------------------------------------------------------------------
// Column stats via MFMA: per block 128(T) x 128(S) scores of one head;
// per-(b,s) partial (max,sumexp) over the 128 t's -> pm/pc[(b*S+s)*128 + h*8 + ty]
// ---------------------------------------------------------------------------
__global__ __launch_bounds__(256) void k_colstats(const ushort* __restrict__ Qh,
                                                  const ushort* __restrict__ Kh,
                                                  const float* __restrict__ bias,
                                                  const int* __restrict__ mask,
                                                  float* __restrict__ pm,
                                                  float* __restrict__ pc) {
  __shared__ ushort Qt[128][72];  // stride 72 bf16 = 144 B (16B-aligned)
  __shared__ ushort Kt[128][72];
  __shared__ float sm2[2][128], sc2[2][128];
  const int bh = blockIdx.z, b = bh >> 4, h = bh & 15;
  const int s0 = blockIdx.x * 128, t0 = blockIdx.y * 128;
  const int tid = threadIdx.x, l = tid & 63, w = tid >> 6;
  const int wm = (w >> 1), wn = (w & 1);
  const int r16 = l & 15, g = l >> 4;

  const ushort* qsrc = Qh + ((size_t)(b * H_ + h) * 1024 + t0) * DH_;
  const ushort* ksrc = Kh + ((size_t)(b * H_ + h) * 1024 + s0) * DH_;
#pragma unroll
  for (int u = 0; u < 4; ++u) {
    const int lin = u * 256 + tid;
    const int row = lin >> 3, c8 = (lin & 7) << 3;
    *(uint4*)&Qt[row][c8] = *(const uint4*)&qsrc[(size_t)row * DH_ + c8];
    *(uint4*)&Kt[row][c8] = *(const uint4*)&ksrc[(size_t)row * DH_ + c8];
  }
  __syncthreads();

  f32x4 acc[4][4] = {};
#pragma unroll
  for (int kc = 0; kc < 2; ++kc) {
    short8 a0[4], b0[4];
#pragma unroll
    for (int i = 0; i < 4; ++i) a0[i] = *(const short8*)&Qt[wm * 64 + 16 * i + r16][kc * 32 + g * 8];
#pragma unroll
    for (int j = 0; j < 4; ++j) b0[j] = *(const short8*)&Kt[wn * 64 + 16 * j + r16][kc * 32 + g * 8];
#pragma unroll
    for (int i = 0; i < 4; ++i)
#pragma unroll
      for (int j = 0; j < 4; ++j)
        acc[i][j] = MFMA_BF16(a0[i], b0[j], acc[i][j], 0, 0, 0);
  }

  float m4[4] = {-INFINITY, -INFINITY, -INFINITY, -INFINITY};
  float c4[4] = {0.f, 0.f, 0.f, 0.f};
#pragma unroll
  for (int j = 0; j < 4; ++j) {
    const int s = s0 + wn * 64 + 16 * j + r16;
#pragma unroll
    for (int i = 0; i < 4; ++i) {
      const int tb = t0 + wm * 64 + 16 * i + 4 * g;
#pragma unroll
      for (int r = 0; r < 4; ++r) {
        const int t = tb + r;
        const float x = acc[i][j][r] + bias[((size_t)h * 1024 + t) * 1024 + s];
        const int mk = mask[(size_t)t * 1024 + s];
        if (!mk) {
          if (x > m4[j]) { c4[j] = c4[j] * __expf(m4[j] - x) + 1.f; m4[j] = x; }
          else           { c4[j] += __expf(x - m4[j]); }
        }
      }
    }
  }
  // reduce across the 4 row-groups (lanes xor 16, 32 share the same column)
#pragma unroll
  for (int j = 0; j < 4; ++j) {
    float mo = __shfl_xor(m4[j], 16), co = __shfl_xor(c4[j], 16);
    mc_comb(m4[j], c4[j], mo, co);
    mo = __shfl_xor(m4[j], 32); co = __shfl_xor(c4[j], 32);
    mc_comb(m4[j], c4[j], mo, co);
  }
  if (g == 0) {
#pragma unroll
    for (int j = 0; j < 4; ++j) {
      sm2[wm][wn * 64 + 16 * j + r16] = m4[j];
      sc2[wm][wn * 64 + 16 * j + r16] = c4[j];
    }
  }
  __syncthreads();
  if (tid < 128) {
    float M = sm2[0][tid], C = sc2[0][tid];
    mc_comb(M, C, sm2[1][tid], sc2[1][tid]);
    const size_t idx = ((size_t)b * 1024 + s0 + tid) * 128 + h * 8 + blockIdx.y;
    pm[idx] = M; pc[idx] = C;
  }
}

// ---------------------------------------------------------------------------
// Combine 128 partials per (b,s) -> M, C.
// ---------------------------------------------------------------------------
__global__ __launch_bounds__(128) void k_combine(const float* __restrict__ pm,
                                                 const float* __restrict__ pc,
                                                 float* __restrict__ Mout,
                                                 float* __restrict__ Cout) {
  const int bs = blockIdx.x, tid = threadIdx.x;
  const float m = pm[(size_t)bs * 128 + tid];
  const float c = pc[(size_t)bs * 128 + tid];
  __shared__ float sm[128], sc[128];
  sm[tid] = m;
  __syncthreads();
  for (int off = 64; off > 0; off >>= 1) {
    if (tid < off) sm[tid] = fmaxf(sm[tid], sm[tid + off]);
    __syncthreads();
  }
  const float M = sm[0];
  __syncthreads();
  sc[tid] = (c > 0.f) ? c * __expf(m - M) : 0.f;
  __syncthreads();
  for (int off = 64; off > 0; off >>= 1) {
    if (tid < off) sc[tid] += sc[tid + off];
    __syncthreads();
  }
  if (tid == 0) { Mout[bs] = M; Cout[bs] = sc[0]; }
}

// ---------------------------------------------------------------------------
// Attention pass: per (b,h,64-t-tile). MFMA scores (identical chain as
// colstats) -> p = exp(x-M)/C -> P bf16 in LDS -> PV MFMA (V transposed in
// LDS) -> row-renormalized O in bf16 [4096,1024].
// ---------------------------------------------------------------------------
__global__ __launch_bounds__(256) void k_attn(const ushort* __restrict__ Qh,
                                              const ushort* __restrict__ Kh,
                                              const ushort* __restrict__ Vh,
                                              const float* __restrict__ bias,
                                              const int* __restrict__ mask,
                                              const float* __restrict__ Mv,
                                              const float* __restrict__ Cv,
                                              ushort* __restrict__ O) {
  __shared__ ushort Qt[64][72];
  __shared__ ushort Kt[128][72];
  __shared__ ushort VtT[64][136];   // [d][s] transposed V chunk
  __shared__ ushort Pt[64][136];    // [t][s] bf16 P
  __shared__ float Msh[128], Cih[128];
  __shared__ float Rp[4][64];
  const int b = blockIdx.z, h = blockIdx.y, t0 = blockIdx.x * 64;
  const int tid = threadIdx.x, l = tid & 63, w = tid >> 6;
  const int r16 = l & 15, g = l >> 4;
  const size_t kvbase = ((size_t)(b * H_ + h) * 1024) * DH_;

  {
    const ushort* qsrc = Qh + ((size_t)(b * H_ + h) * 1024 + t0) * DH_;
#pragma unroll
    for (int u = 0; u < 2; ++u) {
      const int lin = u * 256 + tid;
      const int row = lin >> 3, c8 = (lin & 7) << 3;
      *(uint4*)&Qt[row][c8] = *(const uint4*)&qsrc[(size_t)row * DH_ + c8];
    }
  }
  __syncthreads();
  short8 aq[4][2];
#pragma unroll
  for (int i = 0; i < 4; ++i)
#pragma unroll
    for (int kc = 0; kc < 2; ++kc)
      aq[i][kc] = *(const short8*)&Qt[16 * i + r16][kc * 32 + g * 8];

  f32x4 aco[4] = {};
  float rloc[4][4] = {};

#pragma unroll 1
  for (int sc = 0; sc < 8; ++sc) {
    const int s0 = sc * 128;
    __syncthreads();  // protect Kt/VtT/Pt from previous phase readers
#pragma unroll
    for (int u = 0; u < 4; ++u) {
      const int lin = u * 256 + tid;
      const int row = lin >> 3, c8 = (lin & 7) << 3;
      *(uint4*)&Kt[row][c8] = *(const uint4*)&Kh[kvbase + (size_t)(s0 + row) * DH_ + c8];
    }
    {
      const int s = tid & 127, dh = tid >> 7;
#pragma unroll
      for (int q4 = 0; q4 < 4; ++q4) {
        const int d0 = dh * 32 + q4 * 8;
        uint4 pk = *(const uint4*)&Vh[kvbase + (size_t)(s0 + s) * DH_ + d0];
        const ushort* pv = (const ushort*)&pk;
#pragma unroll
        for (int jj = 0; jj < 8; ++jj) VtT[d0 + jj][s] = pv[jj];
      }
    }
    if (tid < 128) {
      Msh[tid] = Mv[(size_t)b * 1024 + s0 + tid];
      const float c = Cv[(size_t)b * 1024 + s0 + tid];
      Cih[tid] = (c > 0.f) ? 1.f / c : 0.f;
    }
    __syncthreads();

    // scores: wave w owns j-frags {2w, 2w+1}
#pragma unroll
    for (int j2 = 0; j2 < 2; ++j2) {
      const int jf = 2 * w + j2;
      short8 bk0 = *(const short8*)&Kt[16 * jf + r16][g * 8];
      short8 bk1 = *(const short8*)&Kt[16 * jf + r16][32 + g * 8];
      f32x4 as[4] = {};
#pragma unroll
      for (int i = 0; i < 4; ++i) {
        as[i] = MFMA_BF16(aq[i][0], bk0, as[i], 0, 0, 0);
        as[i] = MFMA_BF16(aq[i][1], bk1, as[i], 0, 0, 0);
      }
      const int scol = s0 + 16 * jf + r16;
      const float Mc = Msh[16 * jf + r16];
      const float Cc = Cih[16 * jf + r16];
#pragma unroll
      for (int i = 0; i < 4; ++i) {
        const int tb = t0 + 16 * i + 4 * g;
#pragma unroll
        for (int r = 0; r < 4; ++r) {
          const int t = tb + r;
          const float x = as[i][r] + bias[((size_t)h * 1024 + t) * 1024 + scol];
          const int mk = mask[(size_t)t * 1024 + scol];
          const float p = mk ? 0.f : __expf(x - Mc) * Cc;
          rloc[i][r] += p;
          Pt[16 * i + 4 * g + r][16 * jf + r16] = f2bf(p);
        }
      }
    }
    __syncthreads();

    // PV: wave w owns output rows 16w..16w+15; K=128 in 4 chunks
#pragma unroll
    for (int kc = 0; kc < 4; ++kc) {
      short8 ap = *(const short8*)&Pt[16 * w + r16][kc * 32 + g * 8];
#pragma unroll
      for (int j = 0; j < 4; ++j) {
        short8 bv = *(const short8*)&VtT[16 * j + r16][kc * 32 + g * 8];
        aco[j] = MFMA_BF16(ap, bv, aco[j], 0, 0, 0);
      }
    }
  }

  // row sums: reduce across lanes 1,2,4,8 (same row-group, different cols)
#pragma unroll
  for (int i = 0; i < 4; ++i)
#pragma unroll
    for (int r = 0; r < 4; ++r) {
      float v = rloc[i][r];
      v += __shfl_xor(v, 1); v += __shfl_xor(v, 2);
      v += __shfl_xor(v, 4); v += __shfl_xor(v, 8);
      rloc[i][r] = v;
    }
  if (r16 == 0) {
#pragma unroll
    for (int i = 0; i < 4; ++i)
#pragma unroll
      for (int r = 0; r < 4; ++r)
        Rp[w][16 * i + 4 * g + r] = rloc[i][r];
  }
  __syncthreads();

#pragma unroll
  for (int j = 0; j < 4; ++j)
#pragma unroll
    for (int r = 0; r < 4; ++r) {
      const int tl = 16 * w + 4 * g + r;
      const float R = Rp[0][tl] + Rp[1][tl] + Rp[2][tl] + Rp[3][tl];
      const float o = aco[j][r] / (R + EPSV);
      const int d = 16 * j + r16;
      O[((size_t)(b * 1024) + t0 + tl) * D_ + h * DH_ + d] = f2bf(o);
    }
}

// ---------------------------------------------------------------------------
extern "C" void kernel_launch(void* const* d_in, const int* in_sizes, int n_in,
                              void* d_out, int out_size, void* d_ws, size_t ws_size,
                              hipStream_t stream) {
  (void)in_sizes; (void)n_in; (void)out_size; (void)ws_size;
  const float* q    = (const float*)d_in[0];
  const float* k    = (const float*)d_in[1];
  const float* v    = (const float*)d_in[2];
  const int*   mask = (const int*)d_in[3];
  const float* bias = (const float*)d_in[4];
  const float* Wq   = (const float*)d_in[5];
  const float* Wk   = (const float*)d_in[6];
  const float* Wv   = (const float*)d_in[7];
  const float* Wo   = (const float*)d_in[8];
  float* out = (float*)d_out;

  ushort* qb  = (ushort*)d_ws;          // [4096,1024] bf16
  ushort* kb  = qb + 4194304;
  ushort* vb  = kb + 4194304;
  ushort* Wqb = vb + 4194304;           // [1024,1024] bf16
  ushort* Wkb = Wqb + 1048576;
  ushort* Wvb = Wkb + 1048576;
  ushort* Wob = Wvb + 1048576;
  ushort* Qh  = Wob + 1048576;          // head-split bf16
  ushort* Kh  = Qh + 4194304;
  ushort* Vh  = Kh + 4194304;
  ushort* Ob  = Vh + 4194304;           // attention out bf16 [4096,1024]
  float*  pm  = (float*)(Ob + 4194304); // [B*S,128]
  float*  pc  = pm + 524288;
  float*  Mv  = pc + 524288;            // [B*S]
  float*  Cv  = Mv + 4096;

  k_tobf16<<<4096, 256, 0, stream>>>(q, qb);
  k_tobf16<<<4096, 256, 0, stream>>>(k, kb);
  k_tobf16<<<4096, 256, 0, stream>>>(v, vb);
  k_tobf16<<<1024, 256, 0, stream>>>(Wq, Wqb);
  k_tobf16<<<1024, 256, 0, stream>>>(Wk, Wkb);
  k_tobf16<<<1024, 256, 0, stream>>>(Wv, Wvb);
  k_tobf16<<<1024, 256, 0, stream>>>(Wo, Wob);

  k_gemm<1><<<dim3(32, 8), 256, 0, stream>>>(qb, Wqb, Qh, 0.125f);
  k_gemm<1><<<dim3(32, 8), 256, 0, stream>>>(kb, Wkb, Kh, 1.0f);
  k_gemm<1><<<dim3(32, 8), 256, 0, stream>>>(vb, Wvb, Vh, 1.0f);

  k_colstats<<<dim3(8, 8, 64), 256, 0, stream>>>(Qh, Kh, bias, mask, pm, pc);
  k_combine<<<4096, 128, 0, stream>>>(pm, pc, Mv, Cv);
  k_attn<<<dim3(16, 16, 4), 256, 0, stream>>>(Qh, Kh, Vh, bias, mask, Mv, Cv, Ob);

  k_gemm<0><<<dim3(32, 8), 256, 0, stream>>>(Ob, Wob, out, 1.0f);
}

// Round 3
// 284.995 us; speedup vs baseline: 3.5769x; 2.2557x over previous
//
#include <hip/hip_runtime.h>
#include <hip/hip_bf16.h>
#include <math.h>
#include <stdint.h>

#define B_ 4
#define T_ 1024
#define S_ 1024
#define D_ 1024
#define H_ 16
#define DH_ 64

static constexpr float EPSV = 1e-5f;
static constexpr float NEGV = -1e9f;

typedef __attribute__((ext_vector_type(8))) short short8;
typedef __attribute__((ext_vector_type(4))) float f32x4;

#define MFMA_BF16 __builtin_amdgcn_mfma_f32_16x16x32_bf16

__device__ __forceinline__ ushort f2bf(float f) {
  union { float f; unsigned u; } v; v.f = f;
  unsigned r = (v.u + 0x7FFFu + ((v.u >> 16) & 1u)) >> 16;
  return (ushort)r;
}
__device__ __forceinline__ float bf2f(ushort u) {
  union { unsigned u; float f; } v; v.u = (unsigned)u << 16;
  return v.f;
}

// combine two (max, sumexp) pairs (finite inputs)
__device__ __forceinline__ void mc_comb(float& m, float& c, float mo, float co) {
  float M = fmaxf(m, mo);
  float cn = 0.f;
  if (c  > 0.f) cn += c  * __expf(m  - M);
  if (co > 0.f) cn += co * __expf(mo - M);
  m = M; c = cn;
}

// ---------------------------------------------------------------------------
// f32 -> bf16 elementwise
// ---------------------------------------------------------------------------
__global__ __launch_bounds__(256) void k_tobf16(const float* __restrict__ x,
                                                ushort* __restrict__ y) {
  const int i = (blockIdx.x * 256 + threadIdx.x) * 4;
  float4 v = *(const float4*)(x + i);
  ushort4 o = make_ushort4(f2bf(v.x), f2bf(v.y), f2bf(v.z), f2bf(v.w));
  *(ushort4*)(y + i) = o;
}

// ---------------------------------------------------------------------------
// biasm[h][t][s] = mask[t][s] ? -1e9 : bias[h][t][s]   (bf16)
// ---------------------------------------------------------------------------
__global__ __launch_bounds__(256) void k_fusebias(const float* __restrict__ bias,
                                                  const int* __restrict__ mask,
                                                  ushort* __restrict__ bm) {
  const size_t i = ((size_t)blockIdx.x * 256 + threadIdx.x) * 8;
  const size_t mi = i & (size_t)(T_ * S_ - 1);
  float4 b0 = *(const float4*)(bias + i);
  float4 b1 = *(const float4*)(bias + i + 4);
  int4 m0 = *(const int4*)(mask + mi);
  int4 m1 = *(const int4*)(mask + mi + 4);
  ushort o[8];
  o[0] = f2bf(m0.x ? NEGV : b0.x); o[1] = f2bf(m0.y ? NEGV : b0.y);
  o[2] = f2bf(m0.z ? NEGV : b0.z); o[3] = f2bf(m0.w ? NEGV : b0.w);
  o[4] = f2bf(m1.x ? NEGV : b1.x); o[5] = f2bf(m1.y ? NEGV : b1.y);
  o[6] = f2bf(m1.z ? NEGV : b1.z); o[7] = f2bf(m1.w ? NEGV : b1.w);
  *(uint4*)(bm + i) = *(uint4*)o;
}

// ---------------------------------------------------------------------------
// bf16 MFMA GEMM: Y = A[4096,1024] @ W[1024,1024]^T.
// MODE 0: f32 flat [4096,1024]; MODE 1: bf16 head-split [bh][t][64];
// MODE 2: bf16 head-split TRANSPOSED [bh][d][1024] (for V).
// ---------------------------------------------------------------------------
template <int MODE>
__global__ __launch_bounds__(256) void k_gemm(const ushort* __restrict__ A,
                                              const ushort* __restrict__ W,
                                              void* __restrict__ Yv,
                                              float scale) {
  __shared__ ushort At[128][40];
  __shared__ ushort Wt[128][40];
  const int tid = threadIdx.x;
  const int l = tid & 63, w = tid >> 6;
  const int wm = (w >> 1) * 64, wn = (w & 1) * 64;
  const int r16 = l & 15, g = l >> 4;
  const int i0 = blockIdx.x * 128, j0 = blockIdx.y * 128;
  f32x4 acc[4][4] = {};

  for (int k0 = 0; k0 < D_; k0 += 32) {
    __syncthreads();
#pragma unroll
    for (int u = 0; u < 2; ++u) {
      const int lin = u * 256 + tid;
      const int row = lin >> 2, c8 = (lin & 3) << 3;
      *(uint4*)&At[row][c8] = *(const uint4*)&A[(size_t)(i0 + row) * D_ + k0 + c8];
      *(uint4*)&Wt[row][c8] = *(const uint4*)&W[(size_t)(j0 + row) * D_ + k0 + c8];
    }
    __syncthreads();
    short8 a0[4], b0[4];
#pragma unroll
    for (int i = 0; i < 4; ++i) a0[i] = *(const short8*)&At[wm + 16 * i + r16][g * 8];
#pragma unroll
    for (int j = 0; j < 4; ++j) b0[j] = *(const short8*)&Wt[wn + 16 * j + r16][g * 8];
#pragma unroll
    for (int i = 0; i < 4; ++i)
#pragma unroll
      for (int j = 0; j < 4; ++j)
        acc[i][j] = MFMA_BF16(a0[i], b0[j], acc[i][j], 0, 0, 0);
  }

#pragma unroll
  for (int i = 0; i < 4; ++i)
#pragma unroll
    for (int j = 0; j < 4; ++j)
#pragma unroll
      for (int r = 0; r < 4; ++r) {
        const int row = i0 + wm + 16 * i + 4 * g + r;
        const int col = j0 + wn + 16 * j + r16;
        const float v = acc[i][j][r] * scale;
        if (MODE == 0) {
          ((float*)Yv)[(size_t)row * D_ + col] = v;
        } else if (MODE == 1) {
          const int b = row >> 10, t = row & 1023;
          const int h = col >> 6, dh = col & 63;
          ((ushort*)Yv)[(((size_t)(b * H_ + h) * 1024) + t) * DH_ + dh] = f2bf(v);
        } else {
          const int b = row >> 10, s = row & 1023;
          const int h = col >> 6, dh = col & 63;
          ((ushort*)Yv)[((size_t)(b * H_ + h) * DH_ + dh) * 1024 + s] = f2bf(v);
        }
      }
}

// ---------------------------------------------------------------------------
// Column stats via MFMA + LDS-staged biasm. Per block: 128(T) x 128(S), one
// (b,h). Partials -> pm/pc[(b*S+s)*128 + h*8 + t_tile].
// ---------------------------------------------------------------------------
__global__ __launch_bounds__(256) void k_colstats(const ushort* __restrict__ Qh,
                                                  const ushort* __restrict__ Kh,
                                                  const ushort* __restrict__ biasm,
                                                  float* __restrict__ pm,
                                                  float* __restrict__ pc) {
  __shared__ ushort Qt[128][72];
  __shared__ ushort U[16896];            // union: Kt[128][72] (18432 B) <= Bm[128][132] (33792 B)
  __shared__ float sm2[2][128], sc2[2][128];
  ushort (*Kt)[72] = (ushort(*)[72])U;
  ushort (*Bm)[132] = (ushort(*)[132])U;
  const int bh = blockIdx.z, b = bh >> 4, h = bh & 15;
  const int s0 = blockIdx.x * 128, t0 = blockIdx.y * 128;
  const int tid = threadIdx.x, l = tid & 63, w = tid >> 6;
  const int wm = w >> 1, wn = w & 1;
  const int r16 = l & 15, g = l >> 4;

  const ushort* qsrc = Qh + ((size_t)bh * 1024 + t0) * DH_;
  const ushort* ksrc = Kh + ((size_t)bh * 1024 + s0) * DH_;
#pragma unroll
  for (int u = 0; u < 4; ++u) {
    const int lin = u * 256 + tid;
    const int row = lin >> 3, c8 = (lin & 7) << 3;
    *(uint4*)&Qt[row][c8] = *(const uint4*)&qsrc[(size_t)row * DH_ + c8];
    *(uint4*)&Kt[row][c8] = *(const uint4*)&ksrc[(size_t)row * DH_ + c8];
  }
  __syncthreads();

  f32x4 acc[4][4] = {};
#pragma unroll
  for (int kc = 0; kc < 2; ++kc) {
    short8 a0[4], b0[4];
#pragma unroll
    for (int i = 0; i < 4; ++i) a0[i] = *(const short8*)&Qt[wm * 64 + 16 * i + r16][kc * 32 + g * 8];
#pragma unroll
    for (int j = 0; j < 4; ++j) b0[j] = *(const short8*)&Kt[wn * 64 + 16 * j + r16][kc * 32 + g * 8];
#pragma unroll
    for (int i = 0; i < 4; ++i)
#pragma unroll
      for (int j = 0; j < 4; ++j)
        acc[i][j] = MFMA_BF16(a0[i], b0[j], acc[i][j], 0, 0, 0);
  }
  __syncthreads();   // Kt consumed -> overwrite with Bm

  {
    const ushort* bsrc = biasm + ((size_t)h * 1024 + t0) * 1024 + s0;
#pragma unroll
    for (int u = 0; u < 8; ++u) {
      const int lin = u * 256 + tid;
      const int row = lin >> 4, c8 = (lin & 15) << 3;
      *(uint4*)&Bm[row][c8] = *(const uint4*)&bsrc[(size_t)row * 1024 + c8];
    }
  }
  __syncthreads();

  float m4[4], c4[4];
#pragma unroll
  for (int j = 0; j < 4; ++j) {
    const int sl = wn * 64 + 16 * j + r16;
    float x[16];
#pragma unroll
    for (int i = 0; i < 4; ++i) {
      const int tb = wm * 64 + 16 * i + 4 * g;
#pragma unroll
      for (int r = 0; r < 4; ++r)
        x[i * 4 + r] = acc[i][j][r] + bf2f(Bm[tb + r][sl]);
    }
    float m = x[0];
#pragma unroll
    for (int v = 1; v < 16; ++v) m = fmaxf(m, x[v]);
    float c = 0.f;
#pragma unroll
    for (int v = 0; v < 16; ++v) c += __expf(x[v] - m);
    // reduce across lanes sharing the same column (xor 16, 32)
    float mo = __shfl_xor(m, 16), co = __shfl_xor(c, 16);
    mc_comb(m, c, mo, co);
    mo = __shfl_xor(m, 32); co = __shfl_xor(c, 32);
    mc_comb(m, c, mo, co);
    m4[j] = m; c4[j] = c;
  }
  if (g == 0) {
#pragma unroll
    for (int j = 0; j < 4; ++j) {
      sm2[wm][wn * 64 + 16 * j + r16] = m4[j];
      sc2[wm][wn * 64 + 16 * j + r16] = c4[j];
    }
  }
  __syncthreads();
  if (tid < 128) {
    float M = sm2[0][tid], C = sc2[0][tid];
    mc_comb(M, C, sm2[1][tid], sc2[1][tid]);
    const size_t idx = ((size_t)b * 1024 + s0 + tid) * 128 + h * 8 + blockIdx.y;
    pm[idx] = M; pc[idx] = C;
  }
}

// ---------------------------------------------------------------------------
// Combine 128 partials per (b,s) -> M, C.
// ---------------------------------------------------------------------------
__global__ __launch_bounds__(128) void k_combine(const float* __restrict__ pm,
                                                 const float* __restrict__ pc,
                                                 float* __restrict__ Mout,
                                                 float* __restrict__ Cout) {
  const int bs = blockIdx.x, tid = threadIdx.x;
  const float m = pm[(size_t)bs * 128 + tid];
  const float c = pc[(size_t)bs * 128 + tid];
  __shared__ float sm[128], sc[128];
  sm[tid] = m;
  __syncthreads();
  for (int off = 64; off > 0; off >>= 1) {
    if (tid < off) sm[tid] = fmaxf(sm[tid], sm[tid + off]);
    __syncthreads();
  }
  const float M = sm[0];
  __syncthreads();
  sc[tid] = (c > 0.f) ? c * __expf(m - M) : 0.f;
  __syncthreads();
  for (int off = 64; off > 0; off >>= 1) {
    if (tid < off) sc[tid] += sc[tid + off];
    __syncthreads();
  }
  if (tid == 0) { Mout[bs] = M; Cout[bs] = sc[0]; }
}

// ---------------------------------------------------------------------------
// Attention pass: per (b,h,64-t-tile). QK MFMA + LDS-staged biasm,
// p = exp(x-M)/C, PV MFMA with pre-transposed V, row-renormalized bf16 out.
// ---------------------------------------------------------------------------
__global__ __launch_bounds__(256) void k_attn(const ushort* __restrict__ Qh,
                                              const ushort* __restrict__ Kh,
                                              const ushort* __restrict__ VhT,
                                              const ushort* __restrict__ biasm,
                                              const float* __restrict__ Mv,
                                              const float* __restrict__ Cv,
                                              ushort* __restrict__ O) {
  __shared__ ushort Qt[64][72];
  __shared__ ushort U[9216];             // union: Kt[128][72] (18432 B) >= Bm[64][132] (16896 B)
  __shared__ ushort VtT[64][132];
  __shared__ ushort Pt[64][132];
  __shared__ float Msh[128], Cih[128];
  __shared__ float Rp[4][64];
  ushort (*Kt)[72] = (ushort(*)[72])U;
  ushort (*Bm)[132] = (ushort(*)[132])U;

  const int b = blockIdx.z, h = blockIdx.y, t0 = blockIdx.x * 64;
  const int bh = b * H_ + h;
  const int tid = threadIdx.x, l = tid & 63, w = tid >> 6;
  const int r16 = l & 15, g = l >> 4;
  const size_t kvbase = (size_t)bh * 1024 * DH_;

  {
    const ushort* qsrc = Qh + ((size_t)bh * 1024 + t0) * DH_;
#pragma unroll
    for (int u = 0; u < 2; ++u) {
      const int lin = u * 256 + tid;
      const int row = lin >> 3, c8 = (lin & 7) << 3;
      *(uint4*)&Qt[row][c8] = *(const uint4*)&qsrc[(size_t)row * DH_ + c8];
    }
  }
  __syncthreads();
  short8 aq[4][2];
#pragma unroll
  for (int i = 0; i < 4; ++i)
#pragma unroll
    for (int kc = 0; kc < 2; ++kc)
      aq[i][kc] = *(const short8*)&Qt[16 * i + r16][kc * 32 + g * 8];

  f32x4 aco[4] = {};
  float rloc[4][4] = {};

#pragma unroll 1
  for (int sc = 0; sc < 8; ++sc) {
    const int s0c = sc * 128;
    __syncthreads();  // previous Pt/VtT/U consumed
#pragma unroll
    for (int u = 0; u < 4; ++u) {
      const int lin = u * 256 + tid;
      const int row = lin >> 3, c8 = (lin & 7) << 3;
      *(uint4*)&Kt[row][c8] = *(const uint4*)&Kh[kvbase + (size_t)(s0c + row) * DH_ + c8];
    }
#pragma unroll
    for (int u = 0; u < 4; ++u) {
      const int lin = u * 256 + tid;
      const int row = lin >> 4, c8 = (lin & 15) << 3;
      *(uint4*)&VtT[row][c8] = *(const uint4*)&VhT[((size_t)bh * DH_ + row) * 1024 + s0c + c8];
    }
    if (tid < 128) {
      Msh[tid] = Mv[(size_t)b * 1024 + s0c + tid];
      const float c = Cv[(size_t)b * 1024 + s0c + tid];
      Cih[tid] = (c > 0.f) ? 1.f / c : 0.f;
    }
    __syncthreads();

    // QK: wave w owns j-frags {2w, 2w+1}
    f32x4 as2[2][4] = {};
#pragma unroll
    for (int j2 = 0; j2 < 2; ++j2) {
      const int jf = 2 * w + j2;
      short8 bk0 = *(const short8*)&Kt[16 * jf + r16][g * 8];
      short8 bk1 = *(const short8*)&Kt[16 * jf + r16][32 + g * 8];
#pragma unroll
      for (int i = 0; i < 4; ++i) {
        as2[j2][i] = MFMA_BF16(aq[i][0], bk0, as2[j2][i], 0, 0, 0);
        as2[j2][i] = MFMA_BF16(aq[i][1], bk1, as2[j2][i], 0, 0, 0);
      }
    }
    __syncthreads();  // Kt consumed -> Bm
#pragma unroll
    for (int u = 0; u < 4; ++u) {
      const int lin = u * 256 + tid;
      const int row = lin >> 4, c8 = (lin & 15) << 3;
      *(uint4*)&Bm[row][c8] = *(const uint4*)&biasm[((size_t)h * 1024 + t0 + row) * 1024 + s0c + c8];
    }
    __syncthreads();

    // scores -> P
#pragma unroll
    for (int j2 = 0; j2 < 2; ++j2) {
      const int jf = 2 * w + j2;
      const int sl = 16 * jf + r16;
      const float Mc = Msh[sl];
      const float Cc = Cih[sl];
#pragma unroll
      for (int i = 0; i < 4; ++i) {
        const int tb = 16 * i + 4 * g;
#pragma unroll
        for (int r = 0; r < 4; ++r) {
          const float x = as2[j2][i][r] + bf2f(Bm[tb + r][sl]);
          const float p = __expf(x - Mc) * Cc;
          rloc[i][r] += p;
          Pt[tb + r][sl] = f2bf(p);
        }
      }
    }
    __syncthreads();

    // PV: wave w owns t-rows 16w..16w+15; K=128 in 4 chunks
#pragma unroll
    for (int kc = 0; kc < 4; ++kc) {
      short8 ap = *(const short8*)&Pt[16 * w + r16][kc * 32 + g * 8];
#pragma unroll
      for (int j = 0; j < 4; ++j) {
        short8 bv = *(const short8*)&VtT[16 * j + r16][kc * 32 + g * 8];
        aco[j] = MFMA_BF16(ap, bv, aco[j], 0, 0, 0);
      }
    }
  }

  // row sums across the 16 lanes of each row-group
#pragma unroll
  for (int i = 0; i < 4; ++i)
#pragma unroll
    for (int r = 0; r < 4; ++r) {
      float v = rloc[i][r];
      v += __shfl_xor(v, 1); v += __shfl_xor(v, 2);
      v += __shfl_xor(v, 4); v += __shfl_xor(v, 8);
      rloc[i][r] = v;
    }
  if (r16 == 0) {
#pragma unroll
    for (int i = 0; i < 4; ++i)
#pragma unroll
      for (int r = 0; r < 4; ++r)
        Rp[w][16 * i + 4 * g + r] = rloc[i][r];
  }
  __syncthreads();

#pragma unroll
  for (int j = 0; j < 4; ++j)
#pragma unroll
    for (int r = 0; r < 4; ++r) {
      const int tl = 16 * w + 4 * g + r;
      const float R = Rp[0][tl] + Rp[1][tl] + Rp[2][tl] + Rp[3][tl];
      const float o = aco[j][r] / (R + EPSV);
      const int d = 16 * j + r16;
      O[((size_t)(b * 1024) + t0 + tl) * D_ + h * DH_ + d] = f2bf(o);
    }
}

// ---------------------------------------------------------------------------
extern "C" void kernel_launch(void* const* d_in, const int* in_sizes, int n_in,
                              void* d_out, int out_size, void* d_ws, size_t ws_size,
                              hipStream_t stream) {
  (void)in_sizes; (void)n_in; (void)out_size; (void)ws_size;
  const float* q    = (const float*)d_in[0];
  const float* k    = (const float*)d_in[1];
  const float* v    = (const float*)d_in[2];
  const int*   mask = (const int*)d_in[3];
  const float* bias = (const float*)d_in[4];
  const float* Wq   = (const float*)d_in[5];
  const float* Wk   = (const float*)d_in[6];
  const float* Wv   = (const float*)d_in[7];
  const float* Wo   = (const float*)d_in[8];
  float* out = (float*)d_out;

  ushort* qb   = (ushort*)d_ws;          // [4096,1024] bf16
  ushort* kb   = qb + 4194304;
  ushort* vb   = kb + 4194304;
  ushort* Wqb  = vb + 4194304;           // [1024,1024] bf16
  ushort* Wkb  = Wqb + 1048576;
  ushort* Wvb  = Wkb + 1048576;
  ushort* Wob  = Wvb + 1048576;
  ushort* Qh   = Wob + 1048576;          // [bh][t][64] bf16
  ushort* Kh   = Qh + 4194304;
  ushort* VhT  = Kh + 4194304;           // [bh][d][1024] bf16 (transposed)
  ushort* Ob   = VhT + 4194304;          // [4096,1024] bf16
  ushort* bm   = Ob + 4194304;           // [16,1024,1024] bf16
  float*  pm   = (float*)(bm + 16777216);
  float*  pc   = pm + 524288;
  float*  Mv   = pc + 524288;
  float*  Cv   = Mv + 4096;

  k_tobf16<<<4096, 256, 0, stream>>>(q, qb);
  k_tobf16<<<4096, 256, 0, stream>>>(k, kb);
  k_tobf16<<<4096, 256, 0, stream>>>(v, vb);
  k_tobf16<<<1024, 256, 0, stream>>>(Wq, Wqb);
  k_tobf16<<<1024, 256, 0, stream>>>(Wk, Wkb);
  k_tobf16<<<1024, 256, 0, stream>>>(Wv, Wvb);
  k_tobf16<<<1024, 256, 0, stream>>>(Wo, Wob);
  k_fusebias<<<8192, 256, 0, stream>>>(bias, mask, bm);

  k_gemm<1><<<dim3(32, 8), 256, 0, stream>>>(qb, Wqb, Qh, 0.125f);
  k_gemm<1><<<dim3(32, 8), 256, 0, stream>>>(kb, Wkb, Kh, 1.0f);
  k_gemm<2><<<dim3(32, 8), 256, 0, stream>>>(vb, Wvb, VhT, 1.0f);

  k_colstats<<<dim3(8, 8, 64), 256, 0, stream>>>(Qh, Kh, bm, pm, pc);
  k_combine<<<4096, 128, 0, stream>>>(pm, pc, Mv, Cv);
  k_attn<<<dim3(16, 16, 4), 256, 0, stream>>>(Qh, Kh, VhT, bm, Mv, Cv, Ob);

  k_gemm<0><<<dim3(32, 8), 256, 0, stream>>>(Ob, Wob, out, 1.0f);
}

// Round 4
// 249.342 us; speedup vs baseline: 4.0883x; 1.1430x over previous
//
#include <hip/hip_runtime.h>
#include <hip/hip_bf16.h>
#include <math.h>
#include <stdint.h>

#define B_ 4
#define T_ 1024
#define S_ 1024
#define D_ 1024
#define H_ 16
#define DH_ 64

static constexpr float EPSV = 1e-5f;
static constexpr float NEGV = -1e9f;

typedef __attribute__((ext_vector_type(8))) short short8;
typedef __attribute__((ext_vector_type(4))) float f32x4;

#define MFMA_BF16 __builtin_amdgcn_mfma_f32_16x16x32_bf16

__device__ __forceinline__ ushort f2bf(float f) {
  union { float f; unsigned u; } v; v.f = f;
  unsigned r = (v.u + 0x7FFFu + ((v.u >> 16) & 1u)) >> 16;
  return (ushort)r;
}
__device__ __forceinline__ float bf2f(ushort u) {
  union { unsigned u; float f; } v; v.u = (unsigned)u << 16;
  return v.f;
}

// ---------------------------------------------------------------------------
// fused f32 -> bf16 for q,k,v (4096 blocks each)
// ---------------------------------------------------------------------------
__global__ __launch_bounds__(256) void k_tobf16_3(const float* __restrict__ a,
                                                  const float* __restrict__ b,
                                                  const float* __restrict__ c,
                                                  ushort* __restrict__ oa,
                                                  ushort* __restrict__ ob,
                                                  ushort* __restrict__ oc) {
  const int which = blockIdx.x >> 12;
  const int local = blockIdx.x & 4095;
  const float* src = (which == 0) ? a : (which == 1) ? b : c;
  ushort* dst = (which == 0) ? oa : (which == 1) ? ob : oc;
  const int i = (local * 256 + threadIdx.x) * 4;
  float4 v = *(const float4*)(src + i);
  ushort4 o = make_ushort4(f2bf(v.x), f2bf(v.y), f2bf(v.z), f2bf(v.w));
  *(ushort4*)(dst + i) = o;
}

// fused f32 -> bf16 for 4 weight matrices (1024 blocks each)
__global__ __launch_bounds__(256) void k_tobf16_w(const float* __restrict__ a,
                                                  const float* __restrict__ b,
                                                  const float* __restrict__ c,
                                                  const float* __restrict__ d,
                                                  ushort* __restrict__ oa,
                                                  ushort* __restrict__ ob,
                                                  ushort* __restrict__ oc,
                                                  ushort* __restrict__ od) {
  const int which = blockIdx.x >> 10;
  const int local = blockIdx.x & 1023;
  const float* src = (which == 0) ? a : (which == 1) ? b : (which == 2) ? c : d;
  ushort* dst = (which == 0) ? oa : (which == 1) ? ob : (which == 2) ? oc : od;
  const int i = (local * 256 + threadIdx.x) * 4;
  float4 v = *(const float4*)(src + i);
  ushort4 o = make_ushort4(f2bf(v.x), f2bf(v.y), f2bf(v.z), f2bf(v.w));
  *(ushort4*)(dst + i) = o;
}

// ---------------------------------------------------------------------------
// biasm[h][t][s] = mask[t][s] ? -1e9 : bias[h][t][s]   (bf16)
// ---------------------------------------------------------------------------
__global__ __launch_bounds__(256) void k_fusebias(const float* __restrict__ bias,
                                                  const int* __restrict__ mask,
                                                  ushort* __restrict__ bm) {
  const size_t i = ((size_t)blockIdx.x * 256 + threadIdx.x) * 8;
  const size_t mi = i & (size_t)(T_ * S_ - 1);
  float4 b0 = *(const float4*)(bias + i);
  float4 b1 = *(const float4*)(bias + i + 4);
  int4 m0 = *(const int4*)(mask + mi);
  int4 m1 = *(const int4*)(mask + mi + 4);
  ushort o[8];
  o[0] = f2bf(m0.x ? NEGV : b0.x); o[1] = f2bf(m0.y ? NEGV : b0.y);
  o[2] = f2bf(m0.z ? NEGV : b0.z); o[3] = f2bf(m0.w ? NEGV : b0.w);
  o[4] = f2bf(m1.x ? NEGV : b1.x); o[5] = f2bf(m1.y ? NEGV : b1.y);
  o[6] = f2bf(m1.z ? NEGV : b1.z); o[7] = f2bf(m1.w ? NEGV : b1.w);
  *(uint4*)(bm + i) = *(uint4*)o;
}

// ---------------------------------------------------------------------------
// bf16 MFMA GEMM: Y = A[4096,1024] @ W[1024,1024]^T.
// MODE 0: f32 flat; MODE 1: bf16 head-split [bh][t][64];
// MODE 2: bf16 head-split TRANSPOSED [bh][d][1024] (for V).
// ---------------------------------------------------------------------------
template <int MODE>
__global__ __launch_bounds__(256) void k_gemm(const ushort* __restrict__ A,
                                              const ushort* __restrict__ W,
                                              void* __restrict__ Yv,
                                              float scale) {
  __shared__ ushort At[128][40];
  __shared__ ushort Wt[128][40];
  const int tid = threadIdx.x;
  const int l = tid & 63, w = tid >> 6;
  const int wm = (w >> 1) * 64, wn = (w & 1) * 64;
  const int r16 = l & 15, g = l >> 4;
  const int i0 = blockIdx.x * 128, j0 = blockIdx.y * 128;
  f32x4 acc[4][4] = {};

  for (int k0 = 0; k0 < D_; k0 += 32) {
    __syncthreads();
#pragma unroll
    for (int u = 0; u < 2; ++u) {
      const int lin = u * 256 + tid;
      const int row = lin >> 2, c8 = (lin & 3) << 3;
      *(uint4*)&At[row][c8] = *(const uint4*)&A[(size_t)(i0 + row) * D_ + k0 + c8];
      *(uint4*)&Wt[row][c8] = *(const uint4*)&W[(size_t)(j0 + row) * D_ + k0 + c8];
    }
    __syncthreads();
    short8 a0[4], b0[4];
#pragma unroll
    for (int i = 0; i < 4; ++i) a0[i] = *(const short8*)&At[wm + 16 * i + r16][g * 8];
#pragma unroll
    for (int j = 0; j < 4; ++j) b0[j] = *(const short8*)&Wt[wn + 16 * j + r16][g * 8];
#pragma unroll
    for (int i = 0; i < 4; ++i)
#pragma unroll
      for (int j = 0; j < 4; ++j)
        acc[i][j] = MFMA_BF16(a0[i], b0[j], acc[i][j], 0, 0, 0);
  }

#pragma unroll
  for (int i = 0; i < 4; ++i)
#pragma unroll
    for (int j = 0; j < 4; ++j)
#pragma unroll
      for (int r = 0; r < 4; ++r) {
        const int row = i0 + wm + 16 * i + 4 * g + r;
        const int col = j0 + wn + 16 * j + r16;
        const float v = acc[i][j][r] * scale;
        if (MODE == 0) {
          ((float*)Yv)[(size_t)row * D_ + col] = v;
        } else if (MODE == 1) {
          const int b = row >> 10, t = row & 1023;
          const int h = col >> 6, dh = col & 63;
          ((ushort*)Yv)[(((size_t)(b * H_ + h) * 1024) + t) * DH_ + dh] = f2bf(v);
        } else {
          const int b = row >> 10, s = row & 1023;
          const int h = col >> 6, dh = col & 63;
          ((ushort*)Yv)[((size_t)(b * H_ + h) * DH_ + dh) * 1024 + s] = f2bf(v);
        }
      }
}

// ---------------------------------------------------------------------------
// Column sum-of-exp via MFMA. Block: 128(T) x 128(S), one (b,h).
// Waves = 4 column groups of 32 s; each wave covers all 128 t.
// Bias streamed in 4 double-buffered 32-row chunks through the freed K buffer.
// Partials -> pc[(b*S+s)*128 + h*8 + t_tile].
// grid z = h*4 + b  (batch-sharers 64 blocks apart -> same XCD, L2 reuse).
// ---------------------------------------------------------------------------
__global__ __launch_bounds__(256, 4) void k_colstats(const ushort* __restrict__ Qh,
                                                     const ushort* __restrict__ Kh,
                                                     const ushort* __restrict__ biasm,
                                                     float* __restrict__ pc) {
  __shared__ ushort Qt[128][72];     // 18432 B
  __shared__ ushort U[9216];         // 18432 B: Kt[128][72] OR Bmc[2][32][144]
  ushort (*Kt)[72] = (ushort(*)[72])U;
  typedef ushort Row144[144];
  Row144* Bm0 = (Row144*)U;          // chunk buffer 0: rows [0..32)
  Row144* Bm1 = (Row144*)(U + 4608); // chunk buffer 1

  const int z = blockIdx.z, b = z & 3, h = z >> 2;
  const int s0 = blockIdx.x * 128, t0 = blockIdx.y * 128;
  const int tid = threadIdx.x, l = tid & 63, w = tid >> 6;
  const int r16 = l & 15, g = l >> 4;

  const ushort* qsrc = Qh + ((size_t)((b * H_ + h) * 1024) + t0) * DH_;
  const ushort* ksrc = Kh + ((size_t)((b * H_ + h) * 1024) + s0) * DH_;
#pragma unroll
  for (int u = 0; u < 4; ++u) {
    const int lin = u * 256 + tid;
    const int row = lin >> 3, c8 = (lin & 7) << 3;
    *(uint4*)&Qt[row][c8] = *(const uint4*)&qsrc[(size_t)row * DH_ + c8];
    *(uint4*)&Kt[row][c8] = *(const uint4*)&ksrc[(size_t)row * DH_ + c8];
  }
  __syncthreads();

  f32x4 acc[8][2] = {};
#pragma unroll
  for (int kc = 0; kc < 2; ++kc) {
    short8 bk0 = *(const short8*)&Kt[w * 32 + r16][kc * 32 + g * 8];
    short8 bk1 = *(const short8*)&Kt[w * 32 + 16 + r16][kc * 32 + g * 8];
#pragma unroll
    for (int i = 0; i < 8; ++i) {
      short8 a = *(const short8*)&Qt[16 * i + r16][kc * 32 + g * 8];
      acc[i][0] = MFMA_BF16(a, bk0, acc[i][0], 0, 0, 0);
      acc[i][1] = MFMA_BF16(a, bk1, acc[i][1], 0, 0, 0);
    }
  }
  __syncthreads();   // Kt consumed -> reuse as bias chunk buffers

  const ushort* bsrc = biasm + ((size_t)h * 1024 + t0) * 1024 + s0;
#pragma unroll
  for (int u = 0; u < 2; ++u) {
    const int lin = u * 256 + tid;
    const int row = lin >> 4, c8 = (lin & 15) << 3;
    *(uint4*)&Bm0[row][c8] = *(const uint4*)&bsrc[(size_t)row * 1024 + c8];
  }
  __syncthreads();

  float cs0 = 0.f, cs1 = 0.f;
  const int col0 = w * 32 + r16;
#pragma unroll
  for (int c = 0; c < 4; ++c) {
    Row144* cur = (c & 1) ? Bm1 : Bm0;
    if (c < 3) {
      Row144* nxt = (c & 1) ? Bm0 : Bm1;
#pragma unroll
      for (int u = 0; u < 2; ++u) {
        const int lin = u * 256 + tid;
        const int row = lin >> 4, c8 = (lin & 15) << 3;
        *(uint4*)&nxt[row][c8] =
            *(const uint4*)&bsrc[(size_t)((c + 1) * 32 + row) * 1024 + c8];
      }
    }
#pragma unroll
    for (int ii = 0; ii < 2; ++ii) {
      const int i = 2 * c + ii;
      const int lrow = 16 * ii + 4 * g;
#pragma unroll
      for (int r = 0; r < 4; ++r) {
        cs0 += __expf(acc[i][0][r] + bf2f(cur[lrow + r][col0]));
        cs1 += __expf(acc[i][1][r] + bf2f(cur[lrow + r][col0 + 16]));
      }
    }
    __syncthreads();
  }

  cs0 += __shfl_xor(cs0, 16); cs0 += __shfl_xor(cs0, 32);
  cs1 += __shfl_xor(cs1, 16); cs1 += __shfl_xor(cs1, 32);
  if (g == 0) {
    const size_t base = ((size_t)b * 1024 + s0 + col0) * 128 + h * 8 + blockIdx.y;
    pc[base] = cs0;
    pc[base + 16 * 128] = cs1;
  }
}

// ---------------------------------------------------------------------------
// Combine 128 partial sums per (b,s) -> Civ = 1/C.
// ---------------------------------------------------------------------------
__global__ __launch_bounds__(128) void k_combine(const float* __restrict__ pc,
                                                 float* __restrict__ Civ) {
  const int bs = blockIdx.x, tid = threadIdx.x;
  float c = pc[(size_t)bs * 128 + tid];
  __shared__ float sc[128];
  sc[tid] = c;
  __syncthreads();
  for (int off = 64; off > 0; off >>= 1) {
    if (tid < off) sc[tid] += sc[tid + off];
    __syncthreads();
  }
  if (tid == 0) {
    const float C = sc[0];
    Civ[bs] = (C > 0.f) ? 1.f / C : 0.f;
  }
}

// ---------------------------------------------------------------------------
// Attention pass: per (b,h,64-t-tile). QK MFMA (same chain as colstats),
// p = exp(x)*Ci written IN PLACE over the bias tile, PV MFMA with
// pre-transposed V, row-renormalized bf16 out.
// ---------------------------------------------------------------------------
__global__ __launch_bounds__(256, 3) void k_attn(const ushort* __restrict__ Qh,
                                                 const ushort* __restrict__ Kh,
                                                 const ushort* __restrict__ VhT,
                                                 const ushort* __restrict__ biasm,
                                                 const float* __restrict__ Civ,
                                                 ushort* __restrict__ O) {
  __shared__ ushort Qt[64][72];      // 9216 B
  __shared__ ushort U[9216];         // 18432 B: Kt[128][72] OR BmPt[64][136]
  __shared__ ushort VtT[64][136];    // 17408 B
  __shared__ float Cih[128];
  __shared__ float Rp[4][64];
  ushort (*Kt)[72] = (ushort(*)[72])U;
  ushort (*BmPt)[136] = (ushort(*)[136])U;

  const int b = blockIdx.z, h = blockIdx.y, t0 = blockIdx.x * 64;
  const int bh = b * H_ + h;
  const int tid = threadIdx.x, l = tid & 63, w = tid >> 6;
  const int r16 = l & 15, g = l >> 4;
  const size_t kvbase = (size_t)bh * 1024 * DH_;

  {
    const ushort* qsrc = Qh + ((size_t)bh * 1024 + t0) * DH_;
#pragma unroll
    for (int u = 0; u < 2; ++u) {
      const int lin = u * 256 + tid;
      const int row = lin >> 3, c8 = (lin & 7) << 3;
      *(uint4*)&Qt[row][c8] = *(const uint4*)&qsrc[(size_t)row * DH_ + c8];
    }
  }
  __syncthreads();
  short8 aq[4][2];
#pragma unroll
  for (int i = 0; i < 4; ++i)
#pragma unroll
    for (int kc = 0; kc < 2; ++kc)
      aq[i][kc] = *(const short8*)&Qt[16 * i + r16][kc * 32 + g * 8];

  f32x4 aco[4] = {};
  float rloc[4][4] = {};

#pragma unroll 1
  for (int sc = 0; sc < 8; ++sc) {
    const int s0c = sc * 128;
    __syncthreads();  // previous Pt/VtT consumed
#pragma unroll
    for (int u = 0; u < 4; ++u) {
      const int lin = u * 256 + tid;
      const int row = lin >> 3, c8 = (lin & 7) << 3;
      *(uint4*)&Kt[row][c8] = *(const uint4*)&Kh[kvbase + (size_t)(s0c + row) * DH_ + c8];
    }
#pragma unroll
    for (int u = 0; u < 4; ++u) {
      const int lin = u * 256 + tid;
      const int row = lin >> 4, c8 = (lin & 15) << 3;
      *(uint4*)&VtT[row][c8] = *(const uint4*)&VhT[((size_t)bh * DH_ + row) * 1024 + s0c + c8];
    }
    if (tid < 128) Cih[tid] = Civ[(size_t)b * 1024 + s0c + tid];
    __syncthreads();

    // QK: wave w owns j-frags {2w, 2w+1}
    f32x4 as2[2][4] = {};
#pragma unroll
    for (int j2 = 0; j2 < 2; ++j2) {
      const int jf = 2 * w + j2;
      short8 bk0 = *(const short8*)&Kt[16 * jf + r16][g * 8];
      short8 bk1 = *(const short8*)&Kt[16 * jf + r16][32 + g * 8];
#pragma unroll
      for (int i = 0; i < 4; ++i) {
        as2[j2][i] = MFMA_BF16(aq[i][0], bk0, as2[j2][i], 0, 0, 0);
        as2[j2][i] = MFMA_BF16(aq[i][1], bk1, as2[j2][i], 0, 0, 0);
      }
    }
    __syncthreads();  // Kt consumed -> BmPt
#pragma unroll
    for (int u = 0; u < 4; ++u) {
      const int lin = u * 256 + tid;
      const int row = lin >> 4, c8 = (lin & 15) << 3;
      *(uint4*)&BmPt[row][c8] = *(const uint4*)&biasm[((size_t)h * 1024 + t0 + row) * 1024 + s0c + c8];
    }
    __syncthreads();

    // p = exp(x) * Ci, in place (each element owned by exactly one thread)
#pragma unroll
    for (int j2 = 0; j2 < 2; ++j2) {
      const int jf = 2 * w + j2;
      const int col = 16 * jf + r16;
      const float Cc = Cih[col];
#pragma unroll
      for (int i = 0; i < 4; ++i) {
        const int rowb = 16 * i + 4 * g;
#pragma unroll
        for (int r = 0; r < 4; ++r) {
          const float x = as2[j2][i][r] + bf2f(BmPt[rowb + r][col]);
          const float p = __expf(x) * Cc;
          rloc[i][r] += p;
          BmPt[rowb + r][col] = f2bf(p);
        }
      }
    }
    __syncthreads();

    // PV: wave w owns t-rows 16w..16w+15; K=128 in 4 chunks
#pragma unroll
    for (int kc = 0; kc < 4; ++kc) {
      short8 ap = *(const short8*)&BmPt[16 * w + r16][kc * 32 + g * 8];
#pragma unroll
      for (int j = 0; j < 4; ++j) {
        short8 bv = *(const short8*)&VtT[16 * j + r16][kc * 32 + g * 8];
        aco[j] = MFMA_BF16(ap, bv, aco[j], 0, 0, 0);
      }
    }
  }

  // row sums across the 16 lanes of each row-group
#pragma unroll
  for (int i = 0; i < 4; ++i)
#pragma unroll
    for (int r = 0; r < 4; ++r) {
      float v = rloc[i][r];
      v += __shfl_xor(v, 1); v += __shfl_xor(v, 2);
      v += __shfl_xor(v, 4); v += __shfl_xor(v, 8);
      rloc[i][r] = v;
    }
  if (r16 == 0) {
#pragma unroll
    for (int i = 0; i < 4; ++i)
#pragma unroll
      for (int r = 0; r < 4; ++r)
        Rp[w][16 * i + 4 * g + r] = rloc[i][r];
  }
  __syncthreads();

#pragma unroll
  for (int j = 0; j < 4; ++j)
#pragma unroll
    for (int r = 0; r < 4; ++r) {
      const int tl = 16 * w + 4 * g + r;
      const float R = Rp[0][tl] + Rp[1][tl] + Rp[2][tl] + Rp[3][tl];
      const float o = aco[j][r] / (R + EPSV);
      const int d = 16 * j + r16;
      O[((size_t)(b * 1024) + t0 + tl) * D_ + h * DH_ + d] = f2bf(o);
    }
}

// ---------------------------------------------------------------------------
extern "C" void kernel_launch(void* const* d_in, const int* in_sizes, int n_in,
                              void* d_out, int out_size, void* d_ws, size_t ws_size,
                              hipStream_t stream) {
  (void)in_sizes; (void)n_in; (void)out_size; (void)ws_size;
  const float* q    = (const float*)d_in[0];
  const float* k    = (const float*)d_in[1];
  const float* v    = (const float*)d_in[2];
  const int*   mask = (const int*)d_in[3];
  const float* bias = (const float*)d_in[4];
  const float* Wq   = (const float*)d_in[5];
  const float* Wk   = (const float*)d_in[6];
  const float* Wv   = (const float*)d_in[7];
  const float* Wo   = (const float*)d_in[8];
  float* out = (float*)d_out;

  ushort* qb   = (ushort*)d_ws;          // [4096,1024] bf16
  ushort* kb   = qb + 4194304;
  ushort* vb   = kb + 4194304;
  ushort* Wqb  = vb + 4194304;           // [1024,1024] bf16
  ushort* Wkb  = Wqb + 1048576;
  ushort* Wvb  = Wkb + 1048576;
  ushort* Wob  = Wvb + 1048576;
  ushort* Qh   = Wob + 1048576;          // [bh][t][64] bf16
  ushort* Kh   = Qh + 4194304;
  ushort* VhT  = Kh + 4194304;           // [bh][d][1024] bf16 (transposed)
  ushort* Ob   = VhT + 4194304;          // [4096,1024] bf16
  ushort* bm   = Ob + 4194304;           // [16,1024,1024] bf16
  float*  pc   = (float*)(bm + 16777216);// [B*S,128]
  float*  Civ  = pc + 524288;            // [B*S] reciprocal column sums

  k_tobf16_3<<<12288, 256, 0, stream>>>(q, k, v, qb, kb, vb);
  k_tobf16_w<<<4096, 256, 0, stream>>>(Wq, Wk, Wv, Wo, Wqb, Wkb, Wvb, Wob);
  k_fusebias<<<8192, 256, 0, stream>>>(bias, mask, bm);

  k_gemm<1><<<dim3(32, 8), 256, 0, stream>>>(qb, Wqb, Qh, 0.125f);
  k_gemm<1><<<dim3(32, 8), 256, 0, stream>>>(kb, Wkb, Kh, 1.0f);
  k_gemm<2><<<dim3(32, 8), 256, 0, stream>>>(vb, Wvb, VhT, 1.0f);

  k_colstats<<<dim3(8, 8, 64), 256, 0, stream>>>(Qh, Kh, bm, pc);
  k_combine<<<4096, 128, 0, stream>>>(pc, Civ);
  k_attn<<<dim3(16, 16, 4), 256, 0, stream>>>(Qh, Kh, VhT, bm, Civ, Ob);

  k_gemm<0><<<dim3(32, 8), 256, 0, stream>>>(Ob, Wob, out, 1.0f);
}